// Round 1
// 362.898 us; speedup vs baseline: 1.1503x; 1.1503x over previous
//
#include <hip/hip_runtime.h>

// Problem constants: B=1024, T=200, D=128, H=128
#define T_SZ 200
#define H_SZ 128

typedef __attribute__((ext_vector_type(8))) short    bf16x8;
typedef __attribute__((ext_vector_type(4))) float    f32x4;
typedef __attribute__((ext_vector_type(4))) int      i32x4;
typedef __attribute__((ext_vector_type(2))) unsigned u32x2;

__device__ __forceinline__ unsigned short f2bf(float f) {
  unsigned u = __builtin_bit_cast(unsigned, f);
  u += 0x7fffu + ((u >> 16) & 1u);
  return (unsigned short)(u >> 16);
}
__device__ __forceinline__ float sigmoid_fast(float x) {
  float e = __builtin_amdgcn_exp2f(-1.442695041f * x);
  return __builtin_amdgcn_rcpf(1.0f + e);
}
__device__ __forceinline__ float tanh_fast(float x) {
  float e = __builtin_amdgcn_exp2f(2.885390082f * x);
  return 1.0f - 2.0f * __builtin_amdgcn_rcpf(e + 1.0f);
}
// lgkmcnt(0)-only barrier: does NOT drain vmcnt, so global stores and
// register prefetch loads stay in flight across the barrier.
// 0xc07f = vmcnt(63) expcnt(7) lgkmcnt(0).
__device__ __forceinline__ void ldsbar() {
  __asm__ __volatile__("" ::: "memory");
  __builtin_amdgcn_s_waitcnt(0xc07f);
  __builtin_amdgcn_s_barrier();
  __asm__ __volatile__("" ::: "memory");
}

// ---------------------------------------------------------------------------
// Fused kernel: GRU recurrence with the x-projection computed inline.
// 64 wgs x 512 threads (8 waves = 2/SIMD). Wave w: gate cols [32w,+32)
// (w<4 -> r, w>=4 -> u); cand/h col = 16w+m16.
// Per step: gates = sigmoid(x@Wgx + h@Wgh + bg) (16 MFMA/wave),
//           cand  = tanh(x@Wcx + (r*h)@Wch + bc) (8 MFMA/wave).
// x(t) A-fragments staged in LDS (double-buffered, written one step ahead,
// global loads prefetched 3 steps ahead via a 4-register rotation — every
// ldsbar drains lgkmcnt(0), so stage-reg reuse after >=1 barrier is safe).
// ---------------------------------------------------------------------------
__global__ __launch_bounds__(512, 2) void gru_fused(
    const float* __restrict__ X,    // [B,T,D]
    const int*   __restrict__ seq_len,
    const float* __restrict__ Wg,   // [256,256] rows 0..127 x-part, 128.. h-part
    const float* __restrict__ bg,   // [256]
    const float* __restrict__ Wc,   // [256,128] rows 0..127 x-part, 128.. rh-part
    const float* __restrict__ bc,   // [128]
    float* __restrict__ Y)          // [B,T,H]
{
  __shared__ unsigned short hA[16 * 136];      // h bf16, A-layout [row][k]
  __shared__ unsigned short rhA[16 * 136];     // r*h bf16, A-layout
  __shared__ unsigned short xA[2][16 * 136];   // x bf16, A-layout, dbuf
  __shared__ float hT[128 * 20];               // h fp32 transposed [col][row], b128-friendly
  __shared__ float ubuf[128 * 20];             // u fp32, [col][row]

  const int tid  = threadIdx.x;
  const int lane = tid & 63;
  const int w    = tid >> 6;   // 0..7
  const int m16  = lane & 15;
  const int q    = lane >> 4;

  // ---- weight B-fragments, full K=256 (x-part kb 0..3, h-part kb 4..7) ----
  bf16x8 wgf[2][8];
  float  gbias[2];
  #pragma unroll
  for (int nt = 0; nt < 2; ++nt) {
    int col = w * 32 + nt * 16 + m16;
    gbias[nt] = bg[col];
    #pragma unroll
    for (int kb = 0; kb < 8; ++kb) {
      bf16x8 f;
      #pragma unroll
      for (int j = 0; j < 8; ++j)
        f[j] = (short)f2bf(Wg[(size_t)(kb * 32 + q * 8 + j) * 256 + col]);
      wgf[nt][kb] = f;
    }
  }
  const int colc = w * 16 + m16;  // this wave's cand/h column
  bf16x8 wcf[8];
  float  cbias = bc[colc];
  #pragma unroll
  for (int kb = 0; kb < 8; ++kb) {
    bf16x8 f;
    #pragma unroll
    for (int j = 0; j < 8; ++j)
      f[j] = (short)f2bf(Wc[(size_t)(kb * 32 + q * 8 + j) * 128 + colc]);
    wcf[kb] = f;
  }

  const int bt = blockIdx.x;  // 0..63
  int slen[4];
  #pragma unroll
  for (int i = 0; i < 4; ++i) slen[i] = seq_len[bt * 16 + q * 4 + i];

  float h[4] = {0.f, 0.f, 0.f, 0.f};

  for (int idx = tid; idx < 16 * 136; idx += 512) hA[idx] = 0;
  for (int idx = tid; idx < 128 * 20; idx += 512) hT[idx] = 0.f;

  // ---- x staging: thread loads 4 floats of the 16x128 tile ----
  const int xrow = tid >> 5;        // 0..15
  const int xk4  = (tid & 31) * 4;  // k offset, 4 floats
  const float* xbase = X + (size_t)(bt * 16 + xrow) * T_SZ * 128 + xk4;

  auto xload = [&](int t, f32x4& r) {
    r = *(const f32x4*)(xbase + (size_t)t * 128);
  };
  auto xstage = [&](int buf, const f32x4& r) {
    unsigned d0 = f2bf(r.x) | ((unsigned)f2bf(r.y) << 16);
    unsigned d1 = f2bf(r.z) | ((unsigned)f2bf(r.w) << 16);
    *(u32x2*)&xA[buf][xrow * 136 + xk4] = (u32x2){d0, d1};
  };

  f32x4 xr0, xr1, xr2, xr3;
  xload(0, xr0);
  xstage(0, xr0);      // x(0) -> xA[0]
  xload(1, xr1);       // x(1) staged at step 0
  xload(2, xr2);       // x(2) staged at step 1
  ldsbar();            // covers zero-init + xA[0]

  float* const ybase = Y + (size_t)(bt * 16 + q * 4) * T_SZ * H_SZ + colc;

  auto step = [&](int t, f32x4& xstage_reg, f32x4& xload_reg) {
    // ---- P1: gates ----
    const unsigned short* xb = xA[t & 1];
    bf16x8 xaf[4], haf[4];
    #pragma unroll
    for (int kb = 0; kb < 4; ++kb)
      xaf[kb] = __builtin_bit_cast(bf16x8, *(const i32x4*)&xb[m16 * 136 + kb * 32 + q * 8]);
    #pragma unroll
    for (int kb = 0; kb < 4; ++kb)
      haf[kb] = __builtin_bit_cast(bf16x8, *(const i32x4*)&hA[m16 * 136 + kb * 32 + q * 8]);

    // stage x(t+1) into the other buffer; prefetch x(t+3) into a reg that was
    // staged >=1 barrier ago (lgkm drained -> WAR-safe).
    if (t < 199) xstage((t + 1) & 1, xstage_reg);
    if (t < 197) xload(t + 3, xload_reg);

    // cand x-part now (only needs xaf); carried into P2.
    f32x4 caccx = { cbias, cbias, cbias, cbias };
    #pragma unroll
    for (int kb = 0; kb < 4; ++kb)
      caccx = __builtin_amdgcn_mfma_f32_16x16x32_bf16(xaf[kb], wcf[kb], caccx, 0, 0, 0);

    // gates: split accumulators so the x-chain retires during the hA wait.
    float racc[2][4];
    #pragma unroll
    for (int nt = 0; nt < 2; ++nt) {
      f32x4 ax = { gbias[nt], gbias[nt], gbias[nt], gbias[nt] };
      #pragma unroll
      for (int kb = 0; kb < 4; ++kb)
        ax = __builtin_amdgcn_mfma_f32_16x16x32_bf16(xaf[kb], wgf[nt][kb], ax, 0, 0, 0);
      f32x4 ah = { 0.f, 0.f, 0.f, 0.f };
      #pragma unroll
      for (int kb = 0; kb < 4; ++kb)
        ah = __builtin_amdgcn_mfma_f32_16x16x32_bf16(haf[kb], wgf[nt][kb + 4], ah, 0, 0, 0);
      #pragma unroll
      for (int i = 0; i < 4; ++i) racc[nt][i] = sigmoid_fast(ax[i] + ah[i]);
    }

    if (w < 4) {
      // r-waves: rh = r * h (fp32 from transposed hT, b128 reads) -> bf16 A-layout
      #pragma unroll
      for (int nt = 0; nt < 2; ++nt) {
        int col = w * 32 + nt * 16 + m16;
        f32x4 hv = *(const f32x4*)&hT[col * 20 + q * 4];
        #pragma unroll
        for (int i = 0; i < 4; ++i)
          rhA[(q * 4 + i) * 136 + col] = f2bf(racc[nt][i] * hv[i]);
      }
    } else {
      // u-waves: publish u
      #pragma unroll
      for (int nt = 0; nt < 2; ++nt) {
        int colu = (w - 4) * 32 + nt * 16 + m16;
        f32x4 v = { racc[nt][0], racc[nt][1], racc[nt][2], racc[nt][3] };
        *(f32x4*)&ubuf[colu * 20 + q * 4] = v;
      }
    }
    ldsbar();

    // ---- P2: candidate + h update ----
    bf16x8 rhf[4];
    #pragma unroll
    for (int kb = 0; kb < 4; ++kb)
      rhf[kb] = __builtin_bit_cast(bf16x8, *(const i32x4*)&rhA[m16 * 136 + kb * 32 + q * 8]);
    f32x4 cacc = caccx;
    #pragma unroll
    for (int kb = 0; kb < 4; ++kb)
      cacc = __builtin_amdgcn_mfma_f32_16x16x32_bf16(rhf[kb], wcf[kb + 4], cacc, 0, 0, 0);

    f32x4 uv = *(const f32x4*)&ubuf[colc * 20 + q * 4];
    #pragma unroll
    for (int i = 0; i < 4; ++i) {
      float c  = tanh_fast(cacc[i]);
      float hn = uv[i] * (h[i] - c) + c;   // u*h + (1-u)*c
      bool valid = (t < slen[i]);
      float hv = valid ? hn : h[i];
      h[i] = hv;
      ybase[(size_t)i * T_SZ * H_SZ + (size_t)t * H_SZ] = valid ? hn : 0.0f;
      hA[(q * 4 + i) * 136 + colc] = f2bf(hv);
    }
    *(f32x4*)&hT[colc * 20 + q * 4] = (f32x4){ h[0], h[1], h[2], h[3] };
    ldsbar();
  };

  // 4-step unroll: stage-reg for step t is x(t+1); load-reg receives x(t+3).
  for (int t = 0; t < 200; t += 4) {
    step(t,     xr1, xr3);
    step(t + 1, xr2, xr0);
    step(t + 2, xr3, xr1);
    step(t + 3, xr0, xr2);
  }
}

extern "C" void kernel_launch(void* const* d_in, const int* in_sizes, int n_in,
                              void* d_out, int out_size, void* d_ws, size_t ws_size,
                              hipStream_t stream) {
  const float* X   = (const float*)d_in[0];
  const int*   seq = (const int*)  d_in[1];
  const float* Wg  = (const float*)d_in[2];
  const float* bg  = (const float*)d_in[3];
  const float* Wc  = (const float*)d_in[4];
  const float* bc  = (const float*)d_in[5];
  float* Y = (float*)d_out;
  (void)d_ws; (void)ws_size;  // workspace no longer needed (XGC eliminated)

  hipLaunchKernelGGL(gru_fused, dim3(64), dim3(512), 0, stream,
                     X, seq, Wg, bg, Wc, bc, Y);
}

// Round 2
// 360.982 us; speedup vs baseline: 1.1564x; 1.0053x over previous
//
#include <hip/hip_runtime.h>

// Problem constants: B=1024, T=200, D=128, H=128
#define T_SZ 200
#define H_SZ 128

typedef __attribute__((ext_vector_type(8))) short    bf16x8;
typedef __attribute__((ext_vector_type(4))) float    f32x4;
typedef __attribute__((ext_vector_type(4))) int      i32x4;
typedef __attribute__((ext_vector_type(2))) unsigned u32x2;

__device__ __forceinline__ unsigned short f2bf(float f) {  // weight init only
  unsigned u = __builtin_bit_cast(unsigned, f);
  u += 0x7fffu + ((u >> 16) & 1u);
  return (unsigned short)(u >> 16);
}
// Single-instruction packed f32->bf16 (RNE, same as f2bf): dst = {lo:cvt(a), hi:cvt(b)}
__device__ __forceinline__ unsigned cvt_pk_bf16(float a, float b) {
  unsigned r;
  asm("v_cvt_pk_bf16_f32 %0, %1, %2" : "=v"(r) : "v"(a), "v"(b));
  return r;
}
__device__ __forceinline__ float sigmoid_fast(float x) {
  float e = __builtin_amdgcn_exp2f(-1.442695041f * x);
  return __builtin_amdgcn_rcpf(1.0f + e);
}
__device__ __forceinline__ float tanh_fast(float x) {
  float e = __builtin_amdgcn_exp2f(2.885390082f * x);
  return 1.0f - 2.0f * __builtin_amdgcn_rcpf(e + 1.0f);
}
// lgkmcnt(0)-only barrier: does NOT drain vmcnt, so global stores and
// register prefetch loads stay in flight across the barrier.
// 0xc07f = vmcnt(63) expcnt(7) lgkmcnt(0).
__device__ __forceinline__ void ldsbar() {
  __asm__ __volatile__("" ::: "memory");
  __builtin_amdgcn_s_waitcnt(0xc07f);
  __builtin_amdgcn_s_barrier();
  __asm__ __volatile__("" ::: "memory");
}

// ---------------------------------------------------------------------------
// Fused GRU, software-pipelined across the two LDS-exchange phases:
//   P1(t): gates = sigmoid(ax_pre + h@Wgh)   [ax_pre computed in P2(t-1)]
//   P2(t): cand  = tanh(cc_pre + rh@Wch); h update; xproj(t+1) -> ax/cc_pre
// The 12 x-projection MFMAs are h-independent and fill P2's rhA-read stall,
// so each post-barrier critical path is only: LDS read -> 2-deep MFMA ->
// transcendental -> LDS write. All bf16 conversions via v_cvt_pk_bf16_f32.
// ---------------------------------------------------------------------------
__global__ __launch_bounds__(512, 1) void gru_fused(
    const float* __restrict__ X,    // [B,T,D]
    const int*   __restrict__ seq_len,
    const float* __restrict__ Wg,   // [256,256] rows 0..127 x-part, 128.. h-part
    const float* __restrict__ bg,   // [256]
    const float* __restrict__ Wc,   // [256,128] rows 0..127 x-part, 128.. rh-part
    const float* __restrict__ bc,   // [128]
    float* __restrict__ Y)          // [B,T,H]
{
  __shared__ unsigned short hA[16 * 136];      // h bf16, A-layout [row][k]
  __shared__ unsigned short rhA[16 * 136];     // r*h bf16, A-layout
  __shared__ unsigned short xA[2][16 * 136];   // x bf16, A-layout, dbuf
  __shared__ float hT[128 * 20];               // h fp32 transposed [col][row]
  __shared__ float ubuf[128 * 20];             // u fp32, [col][row]

  const int tid  = threadIdx.x;
  const int lane = tid & 63;
  const int w    = tid >> 6;   // 0..7
  const int m16  = lane & 15;
  const int q    = lane >> 4;

  // ---- weight B-fragments, full K=256 (x-part kb 0..3, h-part kb 4..7) ----
  bf16x8 wgf[2][8];
  float  gbias[2];
  #pragma unroll
  for (int nt = 0; nt < 2; ++nt) {
    int col = w * 32 + nt * 16 + m16;
    gbias[nt] = bg[col];
    #pragma unroll
    for (int kb = 0; kb < 8; ++kb) {
      bf16x8 f;
      #pragma unroll
      for (int j = 0; j < 8; ++j)
        f[j] = (short)f2bf(Wg[(size_t)(kb * 32 + q * 8 + j) * 256 + col]);
      wgf[nt][kb] = f;
    }
  }
  const int colc = w * 16 + m16;  // this wave's cand/h column
  bf16x8 wcf[8];
  float  cbias = bc[colc];
  #pragma unroll
  for (int kb = 0; kb < 8; ++kb) {
    bf16x8 f;
    #pragma unroll
    for (int j = 0; j < 8; ++j)
      f[j] = (short)f2bf(Wc[(size_t)(kb * 32 + q * 8 + j) * 128 + colc]);
    wcf[kb] = f;
  }

  const int bt = blockIdx.x;  // 0..63
  int slen[4];
  #pragma unroll
  for (int i = 0; i < 4; ++i) slen[i] = seq_len[bt * 16 + q * 4 + i];

  float h[4] = {0.f, 0.f, 0.f, 0.f};

  for (int idx = tid; idx < 16 * 136; idx += 512) hA[idx] = 0;
  for (int idx = tid; idx < 128 * 20; idx += 512) hT[idx] = 0.f;

  // ---- x staging: thread loads 4 floats of the 16x128 tile ----
  const int xrow = tid >> 5;        // 0..15
  const int xk4  = (tid & 31) * 4;  // k offset, 4 floats
  const float* xbase = X + (size_t)(bt * 16 + xrow) * T_SZ * 128 + xk4;

  auto xload = [&](int t, f32x4& r) {
    r = *(const f32x4*)(xbase + (size_t)t * 128);
  };
  auto xstage = [&](int buf, const f32x4& r) {
    unsigned d0 = cvt_pk_bf16(r.x, r.y);
    unsigned d1 = cvt_pk_bf16(r.z, r.w);
    *(u32x2*)&xA[buf][xrow * 136 + xk4] = (u32x2){d0, d1};
  };

  // Prologue: x(0),x(1) staged; x(2),x(3) in prefetch regs (2-reg rotation:
  // stage at t consumes x(t+2) from its reg, then reloads x(t+4) into it).
  f32x4 x0r, x1r, xrE, xrO;
  xload(0, x0r); xload(1, x1r);
  xstage(0, x0r); xstage(1, x1r);
  xload(2, xrE); xload(3, xrO);
  ldsbar();  // zero-init + xA[0],xA[1] visible

  // xproj(0): gate-x and cand-x for the first step
  f32x4 axA[2], axB[2], ccA, ccB;
  {
    bf16x8 xaf[4];
    #pragma unroll
    for (int kb = 0; kb < 4; ++kb)
      xaf[kb] = __builtin_bit_cast(bf16x8, *(const i32x4*)&xA[0][m16 * 136 + kb * 32 + q * 8]);
    f32x4 cc = { cbias, cbias, cbias, cbias };
    #pragma unroll
    for (int kb = 0; kb < 4; ++kb)
      cc = __builtin_amdgcn_mfma_f32_16x16x32_bf16(xaf[kb], wcf[kb], cc, 0, 0, 0);
    ccA = cc;
    #pragma unroll
    for (int nt = 0; nt < 2; ++nt) {
      f32x4 a = { gbias[nt], gbias[nt], gbias[nt], gbias[nt] };
      #pragma unroll
      for (int kb = 0; kb < 4; ++kb)
        a = __builtin_amdgcn_mfma_f32_16x16x32_bf16(xaf[kb], wgf[nt][kb], a, 0, 0, 0);
      axA[nt] = a;
    }
  }
  ldsbar();  // prologue xA[0] readers drained before P1(0) overwrites it

  float* const ybase = Y + (size_t)(bt * 16 + q * 4) * T_SZ * H_SZ + colc;

  auto step = [&](int t, f32x4& xreg, f32x4* axin, f32x4& ccin,
                  f32x4* axout, f32x4& ccout) {
    // ---- P1: gates (x-part precomputed; only h-part MFMAs here) ----
    bf16x8 haf[4];
    #pragma unroll
    for (int kb = 0; kb < 4; ++kb)
      haf[kb] = __builtin_bit_cast(bf16x8, *(const i32x4*)&hA[m16 * 136 + kb * 32 + q * 8]);
    f32x4 hv0, hv1;
    if (w < 4) {  // hoisted: h(t-1) ready since last barrier
      hv0 = *(const f32x4*)&hT[(w * 32 + m16) * 20 + q * 4];
      hv1 = *(const f32x4*)&hT[(w * 32 + 16 + m16) * 20 + q * 4];
    }
    // stage x(t+2) into xA[t&1] (readers drained at bar2(t-1)); reload reg
    if (t < 198) xstage(t & 1, xreg);
    if (t < 196) xload(t + 4, xreg);

    float racc[2][4];
    #pragma unroll
    for (int nt = 0; nt < 2; ++nt) {
      // split 4-chain into two 2-chains (halves MFMA dependency latency)
      f32x4 a = { 0.f, 0.f, 0.f, 0.f }, b = { 0.f, 0.f, 0.f, 0.f };
      a = __builtin_amdgcn_mfma_f32_16x16x32_bf16(haf[0], wgf[nt][4], a, 0, 0, 0);
      a = __builtin_amdgcn_mfma_f32_16x16x32_bf16(haf[1], wgf[nt][5], a, 0, 0, 0);
      b = __builtin_amdgcn_mfma_f32_16x16x32_bf16(haf[2], wgf[nt][6], b, 0, 0, 0);
      b = __builtin_amdgcn_mfma_f32_16x16x32_bf16(haf[3], wgf[nt][7], b, 0, 0, 0);
      #pragma unroll
      for (int i = 0; i < 4; ++i)
        racc[nt][i] = sigmoid_fast(axin[nt][i] + a[i] + b[i]);
    }

    if (w < 4) {
      // r-waves: rh = r * h -> bf16 A-layout (cvt_pk pairs, scalar b16 stores)
      #pragma unroll
      for (int nt = 0; nt < 2; ++nt) {
        const f32x4 hv = nt ? hv1 : hv0;
        unsigned p01 = cvt_pk_bf16(racc[nt][0] * hv.x, racc[nt][1] * hv.y);
        unsigned p23 = cvt_pk_bf16(racc[nt][2] * hv.z, racc[nt][3] * hv.w);
        int col = w * 32 + nt * 16 + m16;
        rhA[(q * 4 + 0) * 136 + col] = (unsigned short)(p01 & 0xffffu);
        rhA[(q * 4 + 1) * 136 + col] = (unsigned short)(p01 >> 16);
        rhA[(q * 4 + 2) * 136 + col] = (unsigned short)(p23 & 0xffffu);
        rhA[(q * 4 + 3) * 136 + col] = (unsigned short)(p23 >> 16);
      }
    } else {
      // u-waves: publish u
      #pragma unroll
      for (int nt = 0; nt < 2; ++nt) {
        int colu = (w - 4) * 32 + nt * 16 + m16;
        f32x4 v = { racc[nt][0], racc[nt][1], racc[nt][2], racc[nt][3] };
        *(f32x4*)&ubuf[colu * 20 + q * 4] = v;
      }
    }
    ldsbar();

    // ---- P2: candidate + h update + xproj(t+1) in the rhA-read shadow ----
    bf16x8 xaf2[4];
    if (t < 199) {
      const unsigned short* xb = xA[(t + 1) & 1];
      #pragma unroll
      for (int kb = 0; kb < 4; ++kb)
        xaf2[kb] = __builtin_bit_cast(bf16x8, *(const i32x4*)&xb[m16 * 136 + kb * 32 + q * 8]);
    }
    bf16x8 rhf[4];
    #pragma unroll
    for (int kb = 0; kb < 4; ++kb)
      rhf[kb] = __builtin_bit_cast(bf16x8, *(const i32x4*)&rhA[m16 * 136 + kb * 32 + q * 8]);
    f32x4 uv = *(const f32x4*)&ubuf[colc * 20 + q * 4];

    if (t < 199) {  // xproj(t+1): h-independent, fills the rhf wait
      f32x4 cc = { cbias, cbias, cbias, cbias };
      #pragma unroll
      for (int kb = 0; kb < 4; ++kb)
        cc = __builtin_amdgcn_mfma_f32_16x16x32_bf16(xaf2[kb], wcf[kb], cc, 0, 0, 0);
      ccout = cc;
      #pragma unroll
      for (int nt = 0; nt < 2; ++nt) {
        f32x4 a = { gbias[nt], gbias[nt], gbias[nt], gbias[nt] };
        #pragma unroll
        for (int kb = 0; kb < 4; ++kb)
          a = __builtin_amdgcn_mfma_f32_16x16x32_bf16(xaf2[kb], wgf[nt][kb], a, 0, 0, 0);
        axout[nt] = a;
      }
    }

    f32x4 ca = { 0.f, 0.f, 0.f, 0.f }, cb = { 0.f, 0.f, 0.f, 0.f };
    ca = __builtin_amdgcn_mfma_f32_16x16x32_bf16(rhf[0], wcf[4], ca, 0, 0, 0);
    ca = __builtin_amdgcn_mfma_f32_16x16x32_bf16(rhf[1], wcf[5], ca, 0, 0, 0);
    cb = __builtin_amdgcn_mfma_f32_16x16x32_bf16(rhf[2], wcf[6], cb, 0, 0, 0);
    cb = __builtin_amdgcn_mfma_f32_16x16x32_bf16(rhf[3], wcf[7], cb, 0, 0, 0);

    #pragma unroll
    for (int i = 0; i < 4; ++i) {
      float c  = tanh_fast(ccin[i] + ca[i] + cb[i]);
      float hn = uv[i] * (h[i] - c) + c;   // u*h + (1-u)*c
      bool valid = (t < slen[i]);
      float hvz = valid ? hn : h[i];
      h[i] = hvz;
      ybase[(size_t)i * T_SZ * H_SZ + (size_t)t * H_SZ] = valid ? hn : 0.0f;
    }
    unsigned hp01 = cvt_pk_bf16(h[0], h[1]);
    unsigned hp23 = cvt_pk_bf16(h[2], h[3]);
    hA[(q * 4 + 0) * 136 + colc] = (unsigned short)(hp01 & 0xffffu);
    hA[(q * 4 + 1) * 136 + colc] = (unsigned short)(hp01 >> 16);
    hA[(q * 4 + 2) * 136 + colc] = (unsigned short)(hp23 & 0xffffu);
    hA[(q * 4 + 3) * 136 + colc] = (unsigned short)(hp23 >> 16);
    *(f32x4*)&hT[colc * 20 + q * 4] = (f32x4){ h[0], h[1], h[2], h[3] };
    ldsbar();
  };

  // 2-step unroll rotates {axA,ccA} <-> {axB,ccB} and the x prefetch regs.
  for (int t = 0; t < 200; t += 2) {
    step(t,     xrE, axA, ccA, axB, ccB);
    step(t + 1, xrO, axB, ccB, axA, ccA);
  }
}

extern "C" void kernel_launch(void* const* d_in, const int* in_sizes, int n_in,
                              void* d_out, int out_size, void* d_ws, size_t ws_size,
                              hipStream_t stream) {
  const float* X   = (const float*)d_in[0];
  const int*   seq = (const int*)  d_in[1];
  const float* Wg  = (const float*)d_in[2];
  const float* bg  = (const float*)d_in[3];
  const float* Wc  = (const float*)d_in[4];
  const float* bc  = (const float*)d_in[5];
  float* Y = (float*)d_out;
  (void)d_ws; (void)ws_size;

  hipLaunchKernelGGL(gru_fused, dim3(64), dim3(512), 0, stream,
                     X, seq, Wg, bg, Wc, bc, Y);
}

// Round 3
// 346.624 us; speedup vs baseline: 1.2043x; 1.0414x over previous
//
#include <hip/hip_runtime.h>

// Problem constants: B=1024, T=200, D=128, H=128
#define T_SZ 200
#define H_SZ 128

typedef __attribute__((ext_vector_type(8))) short    bf16x8;
typedef __attribute__((ext_vector_type(4))) float    f32x4;
typedef __attribute__((ext_vector_type(4))) int      i32x4;
typedef __attribute__((ext_vector_type(2))) unsigned u32x2;

__device__ __forceinline__ unsigned short f2bf(float f) {  // weight init only
  unsigned u = __builtin_bit_cast(unsigned, f);
  u += 0x7fffu + ((u >> 16) & 1u);
  return (unsigned short)(u >> 16);
}
// Single-instruction packed f32->bf16 (RNE, same rounding as f2bf).
__device__ __forceinline__ unsigned cvt_pk_bf16(float a, float b) {
  unsigned r;
  asm("v_cvt_pk_bf16_f32 %0, %1, %2" : "=v"(r) : "v"(a), "v"(b));
  return r;
}
__device__ __forceinline__ float sigmoid_fast(float x) {
  float e = __builtin_amdgcn_exp2f(-1.442695041f * x);
  return __builtin_amdgcn_rcpf(1.0f + e);
}
__device__ __forceinline__ float tanh_fast(float x) {
  float e = __builtin_amdgcn_exp2f(2.885390082f * x);
  return 1.0f - 2.0f * __builtin_amdgcn_rcpf(e + 1.0f);
}
// lgkmcnt(0)-only barrier: does NOT drain vmcnt (global stores / register
// prefetch loads stay in flight). 0xc07f = vmcnt(63) expcnt(7) lgkmcnt(0).
__device__ __forceinline__ void ldsbar() {
  __asm__ __volatile__("" ::: "memory");
  __builtin_amdgcn_s_waitcnt(0xc07f);
  __builtin_amdgcn_s_barrier();
  __asm__ __volatile__("" ::: "memory");
}

// ---------------------------------------------------------------------------
// Fused GRU. Column remap so every wave is self-sufficient:
//   wave w owns gate cols [16w,16w+16) (r) and [128+16w,+16) (u),
//   and h/cand col colc = 16w+m16 — all three share the MFMA C-layout
//   (col = m16-tile, rows = q*4+i), so r*h, u, and the h update are pure
//   register ops. hT/ubuf LDS arrays and all wave divergence eliminated.
// Exchanges per step (the structural minimum): hA (h bf16 A-layout) and
// rhA (r*h bf16 A-layout). x-projection (12 MFMAs, h-independent) runs in
// P2's rhf-wait shadow one step ahead; u-sigmoid deferred to P2 likewise.
// ---------------------------------------------------------------------------
__global__ __launch_bounds__(512, 1) void gru_fused(
    const float* __restrict__ X,    // [B,T,D]
    const int*   __restrict__ seq_len,
    const float* __restrict__ Wg,   // [256,256] rows 0..127 x-part, 128.. h-part
    const float* __restrict__ bg,   // [256]
    const float* __restrict__ Wc,   // [256,128] rows 0..127 x-part, 128.. rh-part
    const float* __restrict__ bc,   // [128]
    float* __restrict__ Y)          // [B,T,H]
{
  __shared__ unsigned short hA[16 * 136];      // h bf16, A-layout [row][k]
  __shared__ unsigned short rhA[16 * 136];     // r*h bf16, A-layout
  __shared__ unsigned short xA[2][16 * 136];   // x bf16, A-layout, dbuf

  const int tid  = threadIdx.x;
  const int lane = tid & 63;
  const int w    = tid >> 6;   // 0..7
  const int m16  = lane & 15;
  const int q    = lane >> 4;

  // ---- weight B-fragments (kb 0..3 = x-part rows 0..127, 4..7 = h-part) ----
  // nt=0: r cols 16w..16w+16; nt=1: u cols 128+16w..+16.
  bf16x8 wgf[2][8];
  float  gbias[2];
  #pragma unroll
  for (int nt = 0; nt < 2; ++nt) {
    int col = nt * 128 + w * 16 + m16;
    gbias[nt] = bg[col];
    #pragma unroll
    for (int kb = 0; kb < 8; ++kb) {
      bf16x8 f;
      #pragma unroll
      for (int j = 0; j < 8; ++j)
        f[j] = (short)f2bf(Wg[(size_t)(kb * 32 + q * 8 + j) * 256 + col]);
      wgf[nt][kb] = f;
    }
  }
  const int colc = w * 16 + m16;  // this wave's cand/h column
  bf16x8 wcf[8];
  float  cbias = bc[colc];
  #pragma unroll
  for (int kb = 0; kb < 8; ++kb) {
    bf16x8 f;
    #pragma unroll
    for (int j = 0; j < 8; ++j)
      f[j] = (short)f2bf(Wc[(size_t)(kb * 32 + q * 8 + j) * 128 + colc]);
    wcf[kb] = f;
  }

  const int bt = blockIdx.x;  // 0..63
  int slen[4];
  #pragma unroll
  for (int i = 0; i < 4; ++i) slen[i] = seq_len[bt * 16 + q * 4 + i];

  float h[4] = {0.f, 0.f, 0.f, 0.f};

  for (int idx = tid; idx < 16 * 136; idx += 512) hA[idx] = 0;

  // ---- x staging: thread loads 4 floats of the 16x128 tile ----
  const int xrow = tid >> 5;        // 0..15
  const int xk4  = (tid & 31) * 4;  // k offset, 4 floats
  const float* xbase = X + (size_t)(bt * 16 + xrow) * T_SZ * 128 + xk4;

  auto xload = [&](int t, f32x4& r) {
    r = *(const f32x4*)(xbase + (size_t)t * 128);
  };
  auto xstage = [&](int buf, const f32x4& r) {
    unsigned d0 = cvt_pk_bf16(r.x, r.y);
    unsigned d1 = cvt_pk_bf16(r.z, r.w);
    *(u32x2*)&xA[buf][xrow * 136 + xk4] = (u32x2){d0, d1};
  };

  // Prologue: x(0),x(1) staged; x(2),x(3) in prefetch regs (2-reg rotation:
  // P1(t) stages x(t+2) from its reg, then reloads x(t+4) into it).
  f32x4 x0r, x1r, xrE, xrO;
  xload(0, x0r); xload(1, x1r);
  xstage(0, x0r); xstage(1, x1r);
  xload(2, xrE); xload(3, xrO);
  ldsbar();  // zero-init + xA[0],xA[1] visible

  // xproj(0): gate-x (r,u) and cand-x for the first step
  f32x4 axA[2], axB[2], ccA, ccB;
  {
    bf16x8 xaf[4];
    #pragma unroll
    for (int kb = 0; kb < 4; ++kb)
      xaf[kb] = __builtin_bit_cast(bf16x8, *(const i32x4*)&xA[0][m16 * 136 + kb * 32 + q * 8]);
    f32x4 cc = { cbias, cbias, cbias, cbias };
    #pragma unroll
    for (int kb = 0; kb < 4; ++kb)
      cc = __builtin_amdgcn_mfma_f32_16x16x32_bf16(xaf[kb], wcf[kb], cc, 0, 0, 0);
    ccA = cc;
    #pragma unroll
    for (int nt = 0; nt < 2; ++nt) {
      f32x4 a = { gbias[nt], gbias[nt], gbias[nt], gbias[nt] };
      #pragma unroll
      for (int kb = 0; kb < 4; ++kb)
        a = __builtin_amdgcn_mfma_f32_16x16x32_bf16(xaf[kb], wgf[nt][kb], a, 0, 0, 0);
      axA[nt] = a;
    }
  }
  ldsbar();  // prologue xA[0] readers drained before P1(0) overwrites it

  float* const ybase = Y + (size_t)(bt * 16 + q * 4) * T_SZ * H_SZ + colc;

  auto step = [&](int t, f32x4& xreg, f32x4* axin, f32x4& ccin,
                  f32x4* axout, f32x4& ccout) {
    // ---- P1: r gate + rh publish (critical); u pre-activation only ----
    bf16x8 haf[4];
    #pragma unroll
    for (int kb = 0; kb < 4; ++kb)
      haf[kb] = __builtin_bit_cast(bf16x8, *(const i32x4*)&hA[m16 * 136 + kb * 32 + q * 8]);

    // stage x(t+2) into xA[t&1] (readers drained at bar2(t-1)); reload reg
    if (t < 198) xstage(t & 1, xreg);
    if (t < 196) xload(t + 4, xreg);

    // r: two 2-deep MFMA chains
    f32x4 ra = { 0.f, 0.f, 0.f, 0.f }, rb = { 0.f, 0.f, 0.f, 0.f };
    ra = __builtin_amdgcn_mfma_f32_16x16x32_bf16(haf[0], wgf[0][4], ra, 0, 0, 0);
    ra = __builtin_amdgcn_mfma_f32_16x16x32_bf16(haf[1], wgf[0][5], ra, 0, 0, 0);
    rb = __builtin_amdgcn_mfma_f32_16x16x32_bf16(haf[2], wgf[0][6], rb, 0, 0, 0);
    rb = __builtin_amdgcn_mfma_f32_16x16x32_bf16(haf[3], wgf[0][7], rb, 0, 0, 0);
    // u pre-activation (sigmoid deferred to P2, off P1's critical path)
    f32x4 ua = { 0.f, 0.f, 0.f, 0.f }, ub = { 0.f, 0.f, 0.f, 0.f };
    ua = __builtin_amdgcn_mfma_f32_16x16x32_bf16(haf[0], wgf[1][4], ua, 0, 0, 0);
    ua = __builtin_amdgcn_mfma_f32_16x16x32_bf16(haf[1], wgf[1][5], ua, 0, 0, 0);
    ub = __builtin_amdgcn_mfma_f32_16x16x32_bf16(haf[2], wgf[1][6], ub, 0, 0, 0);
    ub = __builtin_amdgcn_mfma_f32_16x16x32_bf16(haf[3], wgf[1][7], ub, 0, 0, 0);
    f32x4 uacc;
    #pragma unroll
    for (int i = 0; i < 4; ++i) uacc[i] = axin[1][i] + ua[i] + ub[i];

    // rh = sigmoid(r) * h — pure register op (C-layout == h layout)
    float rh0 = sigmoid_fast(axin[0][0] + ra[0] + rb[0]) * h[0];
    float rh1 = sigmoid_fast(axin[0][1] + ra[1] + rb[1]) * h[1];
    float rh2 = sigmoid_fast(axin[0][2] + ra[2] + rb[2]) * h[2];
    float rh3 = sigmoid_fast(axin[0][3] + ra[3] + rb[3]) * h[3];
    unsigned rp01 = cvt_pk_bf16(rh0, rh1);
    unsigned rp23 = cvt_pk_bf16(rh2, rh3);
    rhA[(q * 4 + 0) * 136 + colc] = (unsigned short)(rp01 & 0xffffu);
    rhA[(q * 4 + 1) * 136 + colc] = (unsigned short)(rp01 >> 16);
    rhA[(q * 4 + 2) * 136 + colc] = (unsigned short)(rp23 & 0xffffu);
    rhA[(q * 4 + 3) * 136 + colc] = (unsigned short)(rp23 >> 16);
    ldsbar();

    // ---- P2: candidate + h update + xproj(t+1) in the rhf-wait shadow ----
    bf16x8 rhf[4];
    #pragma unroll
    for (int kb = 0; kb < 4; ++kb)
      rhf[kb] = __builtin_bit_cast(bf16x8, *(const i32x4*)&rhA[m16 * 136 + kb * 32 + q * 8]);
    bf16x8 xaf2[4];
    if (t < 199) {
      const unsigned short* xb = xA[(t + 1) & 1];
      #pragma unroll
      for (int kb = 0; kb < 4; ++kb)
        xaf2[kb] = __builtin_bit_cast(bf16x8, *(const i32x4*)&xb[m16 * 136 + kb * 32 + q * 8]);
    }

    f32x4 ca = { 0.f, 0.f, 0.f, 0.f }, cb = { 0.f, 0.f, 0.f, 0.f };
    ca = __builtin_amdgcn_mfma_f32_16x16x32_bf16(rhf[0], wcf[4], ca, 0, 0, 0);
    ca = __builtin_amdgcn_mfma_f32_16x16x32_bf16(rhf[1], wcf[5], ca, 0, 0, 0);
    cb = __builtin_amdgcn_mfma_f32_16x16x32_bf16(rhf[2], wcf[6], cb, 0, 0, 0);
    cb = __builtin_amdgcn_mfma_f32_16x16x32_bf16(rhf[3], wcf[7], cb, 0, 0, 0);

    if (t < 199) {  // xproj(t+1): h-independent, fills the MFMA/LDS slack
      f32x4 cc = { cbias, cbias, cbias, cbias };
      #pragma unroll
      for (int kb = 0; kb < 4; ++kb)
        cc = __builtin_amdgcn_mfma_f32_16x16x32_bf16(xaf2[kb], wcf[kb], cc, 0, 0, 0);
      ccout = cc;
      #pragma unroll
      for (int nt = 0; nt < 2; ++nt) {
        f32x4 a = { gbias[nt], gbias[nt], gbias[nt], gbias[nt] };
        #pragma unroll
        for (int kb = 0; kb < 4; ++kb)
          a = __builtin_amdgcn_mfma_f32_16x16x32_bf16(xaf2[kb], wgf[nt][kb], a, 0, 0, 0);
        axout[nt] = a;
      }
    }

    // u sigmoid here (hidden under the cand-MFMA wait)
    f32x4 uv;
    #pragma unroll
    for (int i = 0; i < 4; ++i) uv[i] = sigmoid_fast(uacc[i]);

    #pragma unroll
    for (int i = 0; i < 4; ++i) {
      float c  = tanh_fast(ccin[i] + ca[i] + cb[i]);
      float hn = uv[i] * (h[i] - c) + c;   // u*h + (1-u)*c
      bool valid = (t < slen[i]);
      float hvz = valid ? hn : h[i];
      h[i] = hvz;
      ybase[(size_t)i * T_SZ * H_SZ + (size_t)t * H_SZ] = valid ? hn : 0.0f;
    }
    unsigned hp01 = cvt_pk_bf16(h[0], h[1]);
    unsigned hp23 = cvt_pk_bf16(h[2], h[3]);
    hA[(q * 4 + 0) * 136 + colc] = (unsigned short)(hp01 & 0xffffu);
    hA[(q * 4 + 1) * 136 + colc] = (unsigned short)(hp01 >> 16);
    hA[(q * 4 + 2) * 136 + colc] = (unsigned short)(hp23 & 0xffffu);
    hA[(q * 4 + 3) * 136 + colc] = (unsigned short)(hp23 >> 16);
    ldsbar();
  };

  // 2-step unroll rotates {axA,ccA} <-> {axB,ccB} and the x prefetch regs.
  for (int t = 0; t < 200; t += 2) {
    step(t,     xrE, axA, ccA, axB, ccB);
    step(t + 1, xrO, axB, ccB, axA, ccA);
  }
}

extern "C" void kernel_launch(void* const* d_in, const int* in_sizes, int n_in,
                              void* d_out, int out_size, void* d_ws, size_t ws_size,
                              hipStream_t stream) {
  const float* X   = (const float*)d_in[0];
  const int*   seq = (const int*)  d_in[1];
  const float* Wg  = (const float*)d_in[2];
  const float* bg  = (const float*)d_in[3];
  const float* Wc  = (const float*)d_in[4];
  const float* bc  = (const float*)d_in[5];
  float* Y = (float*)d_out;
  (void)d_ws; (void)ws_size;

  hipLaunchKernelGGL(gru_fused, dim3(64), dim3(512), 0, stream,
                     X, seq, Wg, bg, Wc, bc, Y);
}

// Round 4
// 334.217 us; speedup vs baseline: 1.2490x; 1.0371x over previous
//
#include <hip/hip_runtime.h>

// Problem constants: B=1024, T=200, D=128, H=128
#define T_SZ 200
#define H_SZ 128

typedef __attribute__((ext_vector_type(8))) short    bf16x8;
typedef __attribute__((ext_vector_type(4))) float    f32x4;
typedef __attribute__((ext_vector_type(4))) int      i32x4;
typedef __attribute__((ext_vector_type(2))) unsigned u32x2;

__device__ __forceinline__ unsigned short f2bf(float f) {  // weight init only
  unsigned u = __builtin_bit_cast(unsigned, f);
  u += 0x7fffu + ((u >> 16) & 1u);
  return (unsigned short)(u >> 16);
}
// Single-instruction packed f32->bf16 (RNE, same rounding as f2bf).
__device__ __forceinline__ unsigned cvt_pk_bf16(float a, float b) {
  unsigned r;
  asm("v_cvt_pk_bf16_f32 %0, %1, %2" : "=v"(r) : "v"(a), "v"(b));
  return r;
}
__device__ __forceinline__ float sigmoid_fast(float x) {
  float e = __builtin_amdgcn_exp2f(-1.442695041f * x);
  return __builtin_amdgcn_rcpf(1.0f + e);
}
__device__ __forceinline__ float tanh_fast(float x) {
  float e = __builtin_amdgcn_exp2f(2.885390082f * x);
  return 1.0f - 2.0f * __builtin_amdgcn_rcpf(e + 1.0f);
}
// lgkmcnt(0)-only barrier: does NOT drain vmcnt (global stores / register
// prefetch loads stay in flight). 0xc07f = vmcnt(63) expcnt(7) lgkmcnt(0).
__device__ __forceinline__ void ldsbar() {
  __asm__ __volatile__("" ::: "memory");
  __builtin_amdgcn_s_waitcnt(0xc07f);
  __builtin_amdgcn_s_barrier();
  __asm__ __volatile__("" ::: "memory");
}

// ---------------------------------------------------------------------------
// Fused GRU. Wave w owns gate cols [16w,+16) (r) and [128+16w,+16) (u), and
// h/cand col colc = 16w+m16 — C-layout == h register layout, so r*h, u, and
// the h update are pure register ops (no hT/ubuf, no divergence).
// Phase structure (minimal pre-barrier critical paths):
//   P1(t): haf read -> r-MFMA(4, C-init = x-proj) -> sigmoid -> rh publish.
//   P2(t): rhf/xaf reads; u-MFMA(4, register-only inputs: haf held across
//          the barrier) fills the read shadow; cand-MFMA(4) + xproj(t+1)
//          (12 MFMA, h-independent); activations; h publish.
// Pipelined x-projection results are carried as MFMA C-init registers.
// ---------------------------------------------------------------------------
__global__ __launch_bounds__(512, 1) void gru_fused(
    const float* __restrict__ X,    // [B,T,D]
    const int*   __restrict__ seq_len,
    const float* __restrict__ Wg,   // [256,256] rows 0..127 x-part, 128.. h-part
    const float* __restrict__ bg,   // [256]
    const float* __restrict__ Wc,   // [256,128] rows 0..127 x-part, 128.. rh-part
    const float* __restrict__ bc,   // [128]
    float* __restrict__ Y)          // [B,T,H]
{
  __shared__ unsigned short hA[16 * 136];      // h bf16, A-layout [row][k]
  __shared__ unsigned short rhA[16 * 136];     // r*h bf16, A-layout
  __shared__ unsigned short xA[2][16 * 136];   // x bf16, A-layout, dbuf

  const int tid  = threadIdx.x;
  const int lane = tid & 63;
  const int w    = tid >> 6;   // 0..7
  const int m16  = lane & 15;
  const int q    = lane >> 4;

  // ---- weight B-fragments (kb 0..3 = x-part rows 0..127, 4..7 = h-part) ----
  // nt=0: r cols 16w..16w+16; nt=1: u cols 128+16w..+16.
  bf16x8 wgf[2][8];
  float  gbias[2];
  #pragma unroll
  for (int nt = 0; nt < 2; ++nt) {
    int col = nt * 128 + w * 16 + m16;
    gbias[nt] = bg[col];
    #pragma unroll
    for (int kb = 0; kb < 8; ++kb) {
      bf16x8 f;
      #pragma unroll
      for (int j = 0; j < 8; ++j)
        f[j] = (short)f2bf(Wg[(size_t)(kb * 32 + q * 8 + j) * 256 + col]);
      wgf[nt][kb] = f;
    }
  }
  const int colc = w * 16 + m16;  // this wave's cand/h column
  bf16x8 wcf[8];
  float  cbias = bc[colc];
  #pragma unroll
  for (int kb = 0; kb < 8; ++kb) {
    bf16x8 f;
    #pragma unroll
    for (int j = 0; j < 8; ++j)
      f[j] = (short)f2bf(Wc[(size_t)(kb * 32 + q * 8 + j) * 128 + colc]);
    wcf[kb] = f;
  }

  const int bt = blockIdx.x;  // 0..63
  int slen[4];
  #pragma unroll
  for (int i = 0; i < 4; ++i) slen[i] = seq_len[bt * 16 + q * 4 + i];

  float h[4] = {0.f, 0.f, 0.f, 0.f};

  for (int idx = tid; idx < 16 * 136; idx += 512) hA[idx] = 0;

  // ---- x staging: thread loads 4 floats of the 16x128 tile ----
  const int xrow = tid >> 5;        // 0..15
  const int xk4  = (tid & 31) * 4;  // k offset, 4 floats
  const float* xbase = X + (size_t)(bt * 16 + xrow) * T_SZ * 128 + xk4;

  auto xload = [&](int t, f32x4& r) {
    r = *(const f32x4*)(xbase + (size_t)t * 128);
  };
  auto xstage = [&](int buf, const f32x4& r) {
    unsigned d0 = cvt_pk_bf16(r.x, r.y);
    unsigned d1 = cvt_pk_bf16(r.z, r.w);
    *(u32x2*)&xA[buf][xrow * 136 + xk4] = (u32x2){d0, d1};
  };

  // Prologue: x(0),x(1) staged; x(2),x(3) in prefetch regs (2-reg rotation:
  // P1(t) stages x(t+2) from its reg, then reloads x(t+4) into it).
  f32x4 x0r, x1r, xrE, xrO;
  xload(0, x0r); xload(1, x1r);
  xstage(0, x0r); xstage(1, x1r);
  xload(2, xrE); xload(3, xrO);
  ldsbar();  // zero-init + xA[0],xA[1] visible

  // xproj(0): r/u/cand x-parts for the first step (become MFMA C-inits).
  f32x4 axrA, axuA, ccA, axrB, axuB, ccB;
  {
    bf16x8 xaf[4];
    #pragma unroll
    for (int kb = 0; kb < 4; ++kb)
      xaf[kb] = __builtin_bit_cast(bf16x8, *(const i32x4*)&xA[0][m16 * 136 + kb * 32 + q * 8]);
    f32x4 cc = { cbias, cbias, cbias, cbias };
    f32x4 ar = { gbias[0], gbias[0], gbias[0], gbias[0] };
    f32x4 au = { gbias[1], gbias[1], gbias[1], gbias[1] };
    #pragma unroll
    for (int kb = 0; kb < 4; ++kb) {
      cc = __builtin_amdgcn_mfma_f32_16x16x32_bf16(xaf[kb], wcf[kb],    cc, 0, 0, 0);
      ar = __builtin_amdgcn_mfma_f32_16x16x32_bf16(xaf[kb], wgf[0][kb], ar, 0, 0, 0);
      au = __builtin_amdgcn_mfma_f32_16x16x32_bf16(xaf[kb], wgf[1][kb], au, 0, 0, 0);
    }
    ccA = cc; axrA = ar; axuA = au;
  }
  ldsbar();  // prologue xA[0] readers drained before P1(0) overwrites it

  float* const ybase = Y + (size_t)(bt * 16 + q * 4) * T_SZ * H_SZ + colc;

  auto step = [&](int t, f32x4& xreg,
                  f32x4& axin_r, f32x4& axin_u, f32x4& ccin,
                  f32x4& axout_r, f32x4& axout_u, f32x4& ccout) {
    // ---- P1: r gate + rh publish ONLY (minimal pre-barrier path) ----
    bf16x8 haf[4];
    #pragma unroll
    for (int kb = 0; kb < 4; ++kb)
      haf[kb] = __builtin_bit_cast(bf16x8, *(const i32x4*)&hA[m16 * 136 + kb * 32 + q * 8]);

    // stage x(t+2) into xA[t&1] (readers drained at bar2(t-1)); reload reg
    if (t < 198) xstage(t & 1, xreg);
    if (t < 196) xload(t + 4, xreg);

    // r: two 2-deep MFMA chains, C-init carries bias + x-projection
    f32x4 ra = axin_r, rb = { 0.f, 0.f, 0.f, 0.f };
    ra = __builtin_amdgcn_mfma_f32_16x16x32_bf16(haf[0], wgf[0][4], ra, 0, 0, 0);
    ra = __builtin_amdgcn_mfma_f32_16x16x32_bf16(haf[1], wgf[0][5], ra, 0, 0, 0);
    rb = __builtin_amdgcn_mfma_f32_16x16x32_bf16(haf[2], wgf[0][6], rb, 0, 0, 0);
    rb = __builtin_amdgcn_mfma_f32_16x16x32_bf16(haf[3], wgf[0][7], rb, 0, 0, 0);

    // rh = sigmoid(r) * h — pure register op (C-layout == h layout)
    float rh0 = sigmoid_fast(ra[0] + rb[0]) * h[0];
    float rh1 = sigmoid_fast(ra[1] + rb[1]) * h[1];
    float rh2 = sigmoid_fast(ra[2] + rb[2]) * h[2];
    float rh3 = sigmoid_fast(ra[3] + rb[3]) * h[3];
    unsigned rp01 = cvt_pk_bf16(rh0, rh1);
    unsigned rp23 = cvt_pk_bf16(rh2, rh3);
    rhA[(q * 4 + 0) * 136 + colc] = (unsigned short)(rp01 & 0xffffu);
    rhA[(q * 4 + 1) * 136 + colc] = (unsigned short)(rp01 >> 16);
    rhA[(q * 4 + 2) * 136 + colc] = (unsigned short)(rp23 & 0xffffu);
    rhA[(q * 4 + 3) * 136 + colc] = (unsigned short)(rp23 >> 16);
    ldsbar();

    // ---- P2: u (register-only) + candidate + xproj(t+1) + h update ----
    bf16x8 rhf[4];
    #pragma unroll
    for (int kb = 0; kb < 4; ++kb)
      rhf[kb] = __builtin_bit_cast(bf16x8, *(const i32x4*)&rhA[m16 * 136 + kb * 32 + q * 8]);
    bf16x8 xaf2[4];
    if (t < 199) {
      const unsigned short* xb = xA[(t + 1) & 1];
      #pragma unroll
      for (int kb = 0; kb < 4; ++kb)
        xaf2[kb] = __builtin_bit_cast(bf16x8, *(const i32x4*)&xb[m16 * 136 + kb * 32 + q * 8]);
    }

    // u: inputs (haf) already in registers — issues with zero LDS wait,
    // filling the rhf-read shadow.
    f32x4 ua = axin_u, ub = { 0.f, 0.f, 0.f, 0.f };
    ua = __builtin_amdgcn_mfma_f32_16x16x32_bf16(haf[0], wgf[1][4], ua, 0, 0, 0);
    ua = __builtin_amdgcn_mfma_f32_16x16x32_bf16(haf[1], wgf[1][5], ua, 0, 0, 0);
    ub = __builtin_amdgcn_mfma_f32_16x16x32_bf16(haf[2], wgf[1][6], ub, 0, 0, 0);
    ub = __builtin_amdgcn_mfma_f32_16x16x32_bf16(haf[3], wgf[1][7], ub, 0, 0, 0);

    f32x4 ca = ccin, cb = { 0.f, 0.f, 0.f, 0.f };
    ca = __builtin_amdgcn_mfma_f32_16x16x32_bf16(rhf[0], wcf[4], ca, 0, 0, 0);
    ca = __builtin_amdgcn_mfma_f32_16x16x32_bf16(rhf[1], wcf[5], ca, 0, 0, 0);
    cb = __builtin_amdgcn_mfma_f32_16x16x32_bf16(rhf[2], wcf[6], cb, 0, 0, 0);
    cb = __builtin_amdgcn_mfma_f32_16x16x32_bf16(rhf[3], wcf[7], cb, 0, 0, 0);

    if (t < 199) {  // xproj(t+1): h-independent filler
      f32x4 cc = { cbias, cbias, cbias, cbias };
      f32x4 ar = { gbias[0], gbias[0], gbias[0], gbias[0] };
      f32x4 au = { gbias[1], gbias[1], gbias[1], gbias[1] };
      #pragma unroll
      for (int kb = 0; kb < 4; ++kb) {
        cc = __builtin_amdgcn_mfma_f32_16x16x32_bf16(xaf2[kb], wcf[kb],    cc, 0, 0, 0);
        ar = __builtin_amdgcn_mfma_f32_16x16x32_bf16(xaf2[kb], wgf[0][kb], ar, 0, 0, 0);
        au = __builtin_amdgcn_mfma_f32_16x16x32_bf16(xaf2[kb], wgf[1][kb], au, 0, 0, 0);
      }
      ccout = cc; axout_r = ar; axout_u = au;
    }

    f32x4 uv;
    #pragma unroll
    for (int i = 0; i < 4; ++i) uv[i] = sigmoid_fast(ua[i] + ub[i]);

    #pragma unroll
    for (int i = 0; i < 4; ++i) {
      float c  = tanh_fast(ca[i] + cb[i]);
      float hn = uv[i] * (h[i] - c) + c;   // u*h + (1-u)*c
      bool valid = (t < slen[i]);
      float hvz = valid ? hn : h[i];
      h[i] = hvz;
      ybase[(size_t)i * T_SZ * H_SZ + (size_t)t * H_SZ] = valid ? hn : 0.0f;
    }
    unsigned hp01 = cvt_pk_bf16(h[0], h[1]);
    unsigned hp23 = cvt_pk_bf16(h[2], h[3]);
    hA[(q * 4 + 0) * 136 + colc] = (unsigned short)(hp01 & 0xffffu);
    hA[(q * 4 + 1) * 136 + colc] = (unsigned short)(hp01 >> 16);
    hA[(q * 4 + 2) * 136 + colc] = (unsigned short)(hp23 & 0xffffu);
    hA[(q * 4 + 3) * 136 + colc] = (unsigned short)(hp23 >> 16);
    ldsbar();
  };

  // 2-step unroll rotates the {axr,axu,cc} pipeline regs and x prefetch regs.
  for (int t = 0; t < 200; t += 2) {
    step(t,     xrE, axrA, axuA, ccA, axrB, axuB, ccB);
    step(t + 1, xrO, axrB, axuB, ccB, axrA, axuA, ccA);
  }
}

extern "C" void kernel_launch(void* const* d_in, const int* in_sizes, int n_in,
                              void* d_out, int out_size, void* d_ws, size_t ws_size,
                              hipStream_t stream) {
  const float* X   = (const float*)d_in[0];
  const int*   seq = (const int*)  d_in[1];
  const float* Wg  = (const float*)d_in[2];
  const float* bg  = (const float*)d_in[3];
  const float* Wc  = (const float*)d_in[4];
  const float* bc  = (const float*)d_in[5];
  float* Y = (float*)d_out;
  (void)d_ws; (void)ws_size;

  hipLaunchKernelGGL(gru_fused, dim3(64), dim3(512), 0, stream,
                     X, seq, Wg, bg, Wc, bc, Y);
}